// Round 12
// baseline (150.731 us; speedup 1.0000x reference)
//
#include <hip/hip_runtime.h>

#define CC 128
#define NN 4096
#define NB 2
#define NSPLIT 4
#define TK 32
#define ITERS 32   // 1024 keys per split / TK

typedef unsigned short ushort;
typedef unsigned int uint;
typedef __attribute__((ext_vector_type(8))) _Float16 h8;  // 8 f16 (4 VGPRs)
typedef __attribute__((ext_vector_type(8))) short s8;     // 8 bf16 (4 VGPRs)
typedef __attribute__((ext_vector_type(4))) float f4;     // 4 fp32 acc
#define MFMA16(a, b, c) __builtin_amdgcn_mfma_f32_16x16x32_f16(a, b, c, 0, 0, 0)
#define MFMAB(a, b, c)  __builtin_amdgcn_mfma_f32_16x16x32_bf16(a, b, c, 0, 0, 0)

__device__ __forceinline__ ushort f2h(float f) {
  _Float16 h = (_Float16)f;
  return *(ushort*)&h;
}
__device__ __forceinline__ ushort f2bf(float f) {
  uint u = __float_as_uint(f);
  u += 0x7fffu + ((u >> 16) & 1u);   // round-to-nearest-even
  return (ushort)(u >> 16);
}
__device__ __forceinline__ float bf2f(ushort u) {
  return __uint_as_float((uint)u << 16);
}

// ---------------- kernel A: MERGED q/k/v projections (x read ONCE) ----------------
// xs staged once per block (32 n-rows, 4x4 register transpose); which-loop
// re-stages W (L2-hot, 64 KB). Sync pattern per-which identical to the R10
// passing kernel: stage -> barrier -> compute -> barrier.
__global__ __launch_bounds__(256) void qkv_mm(
    const float* __restrict__ x, const float* __restrict__ Wq,
    const float* __restrict__ Wk, const float* __restrict__ Wv,
    ushort* __restrict__ qT, ushort* __restrict__ kT, ushort* __restrict__ vB,
    float* __restrict__ stats) {
  __shared__ ushort Wh[CC][136];     // fp16 W, +8 pad (2-way banks = free)
  __shared__ ushort xs[32][136];     // fp16 x^T tile [n][c]
  const int t = threadIdx.x;
  const int n0 = blockIdx.x * 32;
  const int b = blockIdx.y;

  if (blockIdx.x == 0 && b == 0 && t < 32) stats[t] = 0.f;

  {  // stage x tile with 4x4 register transpose: one slot per thread
    int c0 = (t & 31) * 4;
    int n4 = (t >> 5) * 4;
    float4 r0 = *(const float4*)&x[((size_t)b * CC + c0 + 0) * NN + n0 + n4];
    float4 r1 = *(const float4*)&x[((size_t)b * CC + c0 + 1) * NN + n0 + n4];
    float4 r2 = *(const float4*)&x[((size_t)b * CC + c0 + 2) * NN + n0 + n4];
    float4 r3 = *(const float4*)&x[((size_t)b * CC + c0 + 3) * NN + n0 + n4];
    ushort4 w0, w1, w2, w3;
    w0.x = f2h(r0.x); w0.y = f2h(r1.x); w0.z = f2h(r2.x); w0.w = f2h(r3.x);
    w1.x = f2h(r0.y); w1.y = f2h(r1.y); w1.z = f2h(r2.y); w1.w = f2h(r3.y);
    w2.x = f2h(r0.z); w2.y = f2h(r1.z); w2.z = f2h(r2.z); w2.w = f2h(r3.z);
    w3.x = f2h(r0.w); w3.y = f2h(r1.w); w3.z = f2h(r2.w); w3.w = f2h(r3.w);
    *(ushort4*)&xs[n4 + 0][c0] = w0;
    *(ushort4*)&xs[n4 + 1][c0] = w1;
    *(ushort4*)&xs[n4 + 2][c0] = w2;
    *(ushort4*)&xs[n4 + 3][c0] = w3;
  }
  __syncthreads();                     // xs ready (explicit, conservative)

  const int wv = t >> 6, lane = t & 63;
  const int quad = lane >> 4, l16 = lane & 15;

  for (int which = 0; which < 3; ++which) {
    const float* W = (which == 0) ? Wq : (which == 1) ? Wk : Wv;
#pragma unroll
    for (int i = 0; i < 16; ++i) {     // stage W: fp32 -> fp16
      int slot = t + 256 * i;
      int o = slot >> 5, c4 = (slot & 31) * 4;
      float4 w4 = *(const float4*)&W[o * CC + c4];
      ushort4 p; p.x = f2h(w4.x); p.y = f2h(w4.y); p.z = f2h(w4.z); p.w = f2h(w4.w);
      *(ushort4*)&Wh[o][c4] = p;
    }
    __syncthreads();                   // Wh ready

    if (which < 2) {                   // q,k: D[o][n]
      ushort* out = (which == 0) ? qT : kT;
      f4 acc[2][2];                    // [ot][nt]
#pragma unroll
      for (int ot = 0; ot < 2; ++ot)
#pragma unroll
        for (int nt = 0; nt < 2; ++nt) acc[ot][nt] = (f4){0.f, 0.f, 0.f, 0.f};
#pragma unroll
      for (int kk = 0; kk < 4; ++kk) {
        h8 a0 = *(const h8*)&Wh[(wv * 2 + 0) * 16 + l16][kk * 32 + quad * 8];
        h8 a1 = *(const h8*)&Wh[(wv * 2 + 1) * 16 + l16][kk * 32 + quad * 8];
#pragma unroll
        for (int nt = 0; nt < 2; ++nt) {
          h8 bb = *(const h8*)&xs[nt * 16 + l16][kk * 32 + quad * 8];
          acc[0][nt] = MFMA16(a0, bb, acc[0][nt]);
          acc[1][nt] = MFMA16(a1, bb, acc[1][nt]);
        }
      }
#pragma unroll
      for (int ot = 0; ot < 2; ++ot)
#pragma unroll
        for (int nt = 0; nt < 2; ++nt) {
          f4 a = acc[ot][nt];
          ushort4 p; p.x = f2h(a[0]); p.y = f2h(a[1]); p.z = f2h(a[2]); p.w = f2h(a[3]);
          *(ushort4*)&out[((size_t)b * NN + n0 + nt * 16 + l16) * CC +
                          (wv * 2 + ot) * 16 + quad * 4] = p;
        }
    } else {                           // v: D[n][c]
      f4 acc[2][2];                    // [ci][nt]
#pragma unroll
      for (int ci = 0; ci < 2; ++ci)
#pragma unroll
        for (int nt = 0; nt < 2; ++nt) acc[ci][nt] = (f4){0.f, 0.f, 0.f, 0.f};
#pragma unroll
      for (int kk = 0; kk < 4; ++kk) {
        h8 a0 = *(const h8*)&xs[0 * 16 + l16][kk * 32 + quad * 8];
        h8 a1 = *(const h8*)&xs[1 * 16 + l16][kk * 32 + quad * 8];
        h8 b0 = *(const h8*)&Wh[(wv * 2 + 0) * 16 + l16][kk * 32 + quad * 8];
        h8 b1 = *(const h8*)&Wh[(wv * 2 + 1) * 16 + l16][kk * 32 + quad * 8];
        acc[0][0] = MFMA16(a0, b0, acc[0][0]);
        acc[0][1] = MFMA16(a1, b0, acc[0][1]);
        acc[1][0] = MFMA16(a0, b1, acc[1][0]);
        acc[1][1] = MFMA16(a1, b1, acc[1][1]);
      }
#pragma unroll
      for (int ci = 0; ci < 2; ++ci)
#pragma unroll
        for (int nt = 0; nt < 2; ++nt) {
          f4 a = acc[ci][nt];
          ushort4 p; p.x = f2bf(a[0]); p.y = f2bf(a[1]); p.z = f2bf(a[2]); p.w = f2bf(a[3]);
          *(ushort4*)&vB[((size_t)b * CC + (wv * 2 + ci) * 16 + l16) * NN +
                         n0 + nt * 16 + quad * 4] = p;
        }
    }
    __syncthreads();                   // all reads of Wh done before restage
  }
}

// ---------------- kernel B: 4-way split-K flash attention, MAX-FREE softmax ----
// R10's PROVEN loop structure: stage -> barrier -> prefetch -> compute -> barrier.
// (R11's 1-barrier ping-pong double-buffer produced timing-dependent NaN —
//  reverted; do not reintroduce without a different validation path.)
__global__ __launch_bounds__(256) void attn_split(
    const ushort* __restrict__ qTg, const ushort* __restrict__ kTg,
    const ushort* __restrict__ vBg, ushort* __restrict__ Op,
    float* __restrict__ Lg) {
  __shared__ ushort ksT[TK][136];      // [m][c] fp16, 8.5 KB
  __shared__ ushort vs[CC][40];        // [c][m] bf16, 10 KB
  __shared__ ushort psb[4][16][44];    // per-wave P [q][m] bf16, 5.5 KB

  const int t = threadIdx.x;
  const int b = blockIdx.z;
  const int split = blockIdx.y;
  const int n0 = blockIdx.x * 64;
  const int wv = t >> 6;
  const int lane = t & 63;
  const int quad = lane >> 4;
  const int l16 = lane & 15;
  const int nw = n0 + wv * 16;
  const int m00 = split * (NN / NSPLIT);

  const int krow = t >> 3, kcol = (t & 7) * 8;
  const int vrow = t >> 1, vcol = (t & 1) * 16;
  const ushort* kbp = kTg + ((size_t)b * NN + m00 + krow) * CC + kcol;
  const ushort* vbp = vBg + ((size_t)b * CC + vrow) * NN + m00 + vcol;

  // Q frags direct from global (Q layout [b][n][c] == A-frag layout)
  const size_t qb = ((size_t)b * NN + nw + l16) * CC + quad * 8;
  h8 aq0 = *(const h8*)&qTg[qb + 0 * 32];
  h8 aq1 = *(const h8*)&qTg[qb + 1 * 32];
  h8 aq2 = *(const h8*)&qTg[qb + 2 * 32];
  h8 aq3 = *(const h8*)&qTg[qb + 3 * 32];

  // prefetch tile 0 (NAMED scalars — R4 lesson)
  int4 k0 = *(const int4*)&kbp[0];
  int4 k1 = *(const int4*)&kbp[64];
  int4 v0 = *(const int4*)&vbp[0];
  int4 v1 = *(const int4*)&vbp[8];

  s8 ones;
#pragma unroll
  for (int i = 0; i < 8; ++i) ones[i] = (short)0x3F80;  // bf16 1.0

  f4 o0 = {0,0,0,0}, o1 = {0,0,0,0}, o2 = {0,0,0,0}, o3 = {0,0,0,0};
  f4 o4 = {0,0,0,0}, o5 = {0,0,0,0}, o6 = {0,0,0,0}, o7 = {0,0,0,0};
  f4 oL = {0,0,0,0};

  for (int kt = 0; kt < ITERS; ++kt) {
    *(int4*)&ksT[krow][kcol]      = k0;
    *(int4*)&ksT[krow][kcol + 64] = k1;
    *(int4*)&vs[vrow][vcol]       = v0;
    *(int4*)&vs[vrow][vcol + 8]   = v1;
    __syncthreads();                   // K,V ready

    {  // prefetch next tile (drains over compute)
      int ktn = (kt + 1 < ITERS) ? kt + 1 : kt;
      const ushort* kp = kbp + (size_t)ktn * TK * CC;
      const ushort* vp = vbp + (size_t)ktn * TK;
      k0 = *(const int4*)&kp[0];
      k1 = *(const int4*)&kp[64];
      v0 = *(const int4*)&vp[0];
      v1 = *(const int4*)&vp[8];
    }

    // scores: S[16q][32m], all in-wave
    f4 s0 = {0,0,0,0}, s1 = {0,0,0,0};
#pragma unroll
    for (int kk = 0; kk < 4; ++kk) {
      h8 a = (kk == 0) ? aq0 : (kk == 1) ? aq1 : (kk == 2) ? aq2 : aq3;
      h8 b0 = *(const h8*)&ksT[l16][kk * 32 + quad * 8];
      h8 b1 = *(const h8*)&ksT[16 + l16][kk * 32 + quad * 8];
      s0 = MFMA16(a, b0, s0);
      s1 = MFMA16(a, b1, s1);
    }

    // max-free softmax: straight-line exp + bf16 pack (same-wave LDS, in-order)
#pragma unroll
    for (int r = 0; r < 4; ++r) {
      int row = quad * 4 + r;
      psb[wv][row][l16]      = f2bf(__expf(s0[r]));
      psb[wv][row][16 + l16] = f2bf(__expf(s1[r]));
    }

    // PV (bf16): D[c=128][q=16] (K=32, single step) + L via ones-MFMA
    {
      s8 bp = *(const s8*)&psb[wv][l16][quad * 8];
      s8 a0 = *(const s8*)&vs[0 * 16 + l16][quad * 8];
      s8 a1 = *(const s8*)&vs[1 * 16 + l16][quad * 8];
      s8 a2 = *(const s8*)&vs[2 * 16 + l16][quad * 8];
      s8 a3 = *(const s8*)&vs[3 * 16 + l16][quad * 8];
      o0 = MFMAB(a0, bp, o0);
      o1 = MFMAB(a1, bp, o1);
      o2 = MFMAB(a2, bp, o2);
      o3 = MFMAB(a3, bp, o3);
      s8 a4 = *(const s8*)&vs[4 * 16 + l16][quad * 8];
      s8 a5 = *(const s8*)&vs[5 * 16 + l16][quad * 8];
      s8 a6 = *(const s8*)&vs[6 * 16 + l16][quad * 8];
      s8 a7 = *(const s8*)&vs[7 * 16 + l16][quad * 8];
      o4 = MFMAB(a4, bp, o4);
      o5 = MFMAB(a5, bp, o5);
      o6 = MFMAB(a6, bp, o6);
      o7 = MFMAB(a7, bp, o7);
      oL = MFMAB(ones, bp, oL);
    }
    __syncthreads();                   // all waves done reading ksT/vs
  }

  // epilogue: bf16 O partial [split*NB+b][n][c], packed 8B stores
  if (quad == 0)
    Lg[((size_t)(split * NB + b)) * NN + nw + l16] = oL[0];
  {
    size_t nb_ = ((size_t)(split * NB + b) * NN + nw + l16) * CC + quad * 4;
    ushort4 p;
#define STORE_O(oo, off) \
    p.x = f2bf(oo[0]); p.y = f2bf(oo[1]); p.z = f2bf(oo[2]); p.w = f2bf(oo[3]); \
    *(ushort4*)&Op[nb_ + off] = p;
    STORE_O(o0, 0 * 16) STORE_O(o1, 1 * 16) STORE_O(o2, 2 * 16) STORE_O(o3, 3 * 16)
    STORE_O(o4, 4 * 16) STORE_O(o5, 5 * 16) STORE_O(o6, 6 * 16) STORE_O(o7, 7 * 16)
#undef STORE_O
  }
}

// ---------------- kernel C: combine 4 splits + Wo projection + residual + GN stats ----
__global__ __launch_bounds__(256) void proj_mm(
    const float* __restrict__ x, const float* __restrict__ Wo,
    const ushort* __restrict__ Op, const float* __restrict__ Lg,
    float* __restrict__ y, float* __restrict__ stats) {
  __shared__ ushort Wh[CC][136];
  __shared__ ushort hT[32][136];
  __shared__ float Linv[32];
  const int t = threadIdx.x;
  const int n0 = blockIdx.x * 32;
  const int b = blockIdx.y;

#pragma unroll
  for (int i = 0; i < 16; ++i) {       // stage Wo -> fp16
    int slot = t + 256 * i;
    int o = slot >> 5, c4 = (slot & 31) * 4;
    float4 w4 = *(const float4*)&Wo[o * CC + c4];
    ushort4 p; p.x = f2h(w4.x); p.y = f2h(w4.y); p.z = f2h(w4.z); p.w = f2h(w4.w);
    *(ushort4*)&Wh[o][c4] = p;
  }
  if (t < 32) {
    float l = 0.f;
#pragma unroll
    for (int s = 0; s < NSPLIT; ++s)
      l += Lg[(size_t)(s * NB + b) * NN + n0 + t];
    Linv[t] = 1.f / l;
  }
  __syncthreads();

#pragma unroll
  for (int i = 0; i < 16; ++i) {       // combine 4 bf16 splits -> h^T fp16
    int slot = t + 256 * i;
    int n = slot >> 5, c4 = (slot & 31) * 4;
    size_t base = ((size_t)(n0 + n)) * CC + c4;
    float a0 = 0.f, a1 = 0.f, a2 = 0.f, a3 = 0.f;
#pragma unroll
    for (int s = 0; s < NSPLIT; ++s) {
      ushort4 u = *(const ushort4*)&Op[(size_t)(s * NB + b) * NN * CC + base];
      a0 += bf2f(u.x); a1 += bf2f(u.y); a2 += bf2f(u.z); a3 += bf2f(u.w);
    }
    float li = Linv[n];
    ushort4 p;
    p.x = f2h(a0 * li); p.y = f2h(a1 * li);
    p.z = f2h(a2 * li); p.w = f2h(a3 * li);
    *(ushort4*)&hT[n][c4] = p;
  }
  __syncthreads();

  const int wv = t >> 6, lane = t & 63;
  const int quad = lane >> 4, l16 = lane & 15;

  f4 acc[2][2];                        // [nt][ot]
#pragma unroll
  for (int nt = 0; nt < 2; ++nt)
#pragma unroll
    for (int ot = 0; ot < 2; ++ot) acc[nt][ot] = (f4){0.f, 0.f, 0.f, 0.f};
#pragma unroll
  for (int kk = 0; kk < 4; ++kk) {
    h8 a0 = *(const h8*)&hT[0 * 16 + l16][kk * 32 + quad * 8];
    h8 a1 = *(const h8*)&hT[1 * 16 + l16][kk * 32 + quad * 8];
    h8 b0 = *(const h8*)&Wh[(wv * 2 + 0) * 16 + l16][kk * 32 + quad * 8];
    h8 b1 = *(const h8*)&Wh[(wv * 2 + 1) * 16 + l16][kk * 32 + quad * 8];
    acc[0][0] = MFMA16(a0, b0, acc[0][0]);
    acc[0][1] = MFMA16(a0, b1, acc[0][1]);
    acc[1][0] = MFMA16(a1, b0, acc[1][0]);
    acc[1][1] = MFMA16(a1, b1, acc[1][1]);
  }

#pragma unroll
  for (int ot = 0; ot < 2; ++ot) {     // store y + residual, gather GN stats
    const int o = (wv * 2 + ot) * 16 + l16;
    const int g = wv * 2 + ot;         // group index (16 ch/group)
    float s = 0.f, sq = 0.f;
#pragma unroll
    for (int nt = 0; nt < 2; ++nt) {
      size_t addr = ((size_t)b * CC + o) * NN + n0 + nt * 16 + quad * 4;
      float4 xv = *(const float4*)&x[addr];
      f4 a = acc[nt][ot];
      float4 yy;
      yy.x = a[0] + xv.x; yy.y = a[1] + xv.y;
      yy.z = a[2] + xv.z; yy.w = a[3] + xv.w;
      *(float4*)&y[addr] = yy;
      s += yy.x + yy.y + yy.z + yy.w;
      sq += yy.x * yy.x + yy.y * yy.y + yy.z * yy.z + yy.w * yy.w;
    }
#pragma unroll
    for (int off = 1; off < 64; off <<= 1) {
      s += __shfl_xor(s, off);
      sq += __shfl_xor(sq, off);
    }
    if (lane == 0) {
      atomicAdd(&stats[(b * 8 + g) * 2 + 0], s);
      atomicAdd(&stats[(b * 8 + g) * 2 + 1], sq);
    }
  }
}

// ---------------- kernel D: GroupNorm finalize + affine + SiLU ----------------
__global__ __launch_bounds__(256) void gn_silu(
    const float* __restrict__ y, const float* __restrict__ stats,
    const float* __restrict__ gamma, const float* __restrict__ beta,
    float* __restrict__ out) {
  const int tid = blockIdx.x * 256 + threadIdx.x;
  const int i4 = tid * 4;
  const int c = (i4 >> 12) & (CC - 1);
  const int b = i4 >> 19;
  const int g = c >> 4;
  const float inv = 1.f / 65536.f;
  float sum = stats[(b * 8 + g) * 2 + 0];
  float sq  = stats[(b * 8 + g) * 2 + 1];
  float mean = sum * inv;
  float var = sq * inv - mean * mean;
  float rs = rsqrtf(var + 1e-5f);
  float ga = gamma[c], be = beta[c];
  float4 v4 = *(const float4*)&y[i4];
  float4 r;
  float o;
  o = (v4.x - mean) * rs * ga + be; r.x = o / (1.f + __expf(-o));
  o = (v4.y - mean) * rs * ga + be; r.y = o / (1.f + __expf(-o));
  o = (v4.z - mean) * rs * ga + be; r.z = o / (1.f + __expf(-o));
  o = (v4.w - mean) * rs * ga + be; r.w = o / (1.f + __expf(-o));
  *(float4*)&out[i4] = r;
}

extern "C" void kernel_launch(void* const* d_in, const int* in_sizes, int n_in,
                              void* d_out, int out_size, void* d_ws, size_t ws_size,
                              hipStream_t stream) {
  const float* x     = (const float*)d_in[0];
  const float* Wq    = (const float*)d_in[1];
  const float* Wk    = (const float*)d_in[2];
  const float* Wv    = (const float*)d_in[3];
  const float* Wo    = (const float*)d_in[4];
  const float* gamma = (const float*)d_in[5];
  const float* beta  = (const float*)d_in[6];
  float* out = (float*)d_out;
  float* ws  = (float*)d_ws;

  // ws layout (MiB):
  // [0,8):    O partials bf16 [4 splits][b][n][c]
  // [8,10):   qT fp16; [10,12): kT fp16;  y fp32 overlays [8,12) (qT/kT dead)
  // [12,14):  vB bf16
  // [14,...): Lg (128 KB) + stats (128 B)
  const size_t M = (size_t)NB * CC * NN;  // 1,048,576 elems
  ushort* Op = (ushort*)ws;               // 4*M ushorts = 8 MB
  ushort* qT = (ushort*)(ws + 2 * M);
  ushort* kT = qT + M;
  float* y = ws + 2 * M;
  ushort* vB = kT + M;
  float* Lg = (float*)(vB + M);
  float* stats = Lg + (size_t)NSPLIT * NB * NN;

  qkv_mm<<<dim3(NN / 32, NB), 256, 0, stream>>>(x, Wq, Wk, Wv, qT, kT, vB, stats);
  attn_split<<<dim3(NN / 64, NSPLIT, NB), 256, 0, stream>>>(qT, kT, vB, Op, Lg);
  proj_mm<<<dim3(NN / 32, NB), 256, 0, stream>>>(x, Wo, Op, Lg, y, stats);
  gn_silu<<<dim3((int)(M / 1024)), 256, 0, stream>>>(y, stats, gamma, beta, out);
}

// Round 13
// 148.185 us; speedup vs baseline: 1.0172x; 1.0172x over previous
//
#include <hip/hip_runtime.h>

#define CC 128
#define NN 4096
#define NB 2
#define NSPLIT 4
#define TK 64
#define ITERS 16   // 1024 keys per split / TK

typedef unsigned short ushort;
typedef unsigned int uint;
typedef __attribute__((ext_vector_type(8))) _Float16 h8;  // 8 f16 (4 VGPRs)
typedef __attribute__((ext_vector_type(8))) short s8;     // 8 bf16 (4 VGPRs)
typedef __attribute__((ext_vector_type(4))) float f4;     // 4 fp32 acc
#define MFMA16(a, b, c) __builtin_amdgcn_mfma_f32_16x16x32_f16(a, b, c, 0, 0, 0)
#define MFMAB(a, b, c)  __builtin_amdgcn_mfma_f32_16x16x32_bf16(a, b, c, 0, 0, 0)

__device__ __forceinline__ ushort f2h(float f) {
  _Float16 h = (_Float16)f;
  return *(ushort*)&h;
}
__device__ __forceinline__ ushort f2bf(float f) {
  uint u = __float_as_uint(f);
  u += 0x7fffu + ((u >> 16) & 1u);   // round-to-nearest-even
  return (ushort)(u >> 16);
}
__device__ __forceinline__ float bf2f(ushort u) {
  return __uint_as_float((uint)u << 16);
}

// ---------------- kernel A: MERGED q/k/v projections (x read ONCE) ----------------
// Unchanged from R12 (passing).
__global__ __launch_bounds__(256) void qkv_mm(
    const float* __restrict__ x, const float* __restrict__ Wq,
    const float* __restrict__ Wk, const float* __restrict__ Wv,
    ushort* __restrict__ qT, ushort* __restrict__ kT, ushort* __restrict__ vB,
    float* __restrict__ stats) {
  __shared__ ushort Wh[CC][136];     // fp16 W, +8 pad (2-way banks = free)
  __shared__ ushort xs[32][136];     // fp16 x^T tile [n][c]
  const int t = threadIdx.x;
  const int n0 = blockIdx.x * 32;
  const int b = blockIdx.y;

  if (blockIdx.x == 0 && b == 0 && t < 32) stats[t] = 0.f;

  {  // stage x tile with 4x4 register transpose: one slot per thread
    int c0 = (t & 31) * 4;
    int n4 = (t >> 5) * 4;
    float4 r0 = *(const float4*)&x[((size_t)b * CC + c0 + 0) * NN + n0 + n4];
    float4 r1 = *(const float4*)&x[((size_t)b * CC + c0 + 1) * NN + n0 + n4];
    float4 r2 = *(const float4*)&x[((size_t)b * CC + c0 + 2) * NN + n0 + n4];
    float4 r3 = *(const float4*)&x[((size_t)b * CC + c0 + 3) * NN + n0 + n4];
    ushort4 w0, w1, w2, w3;
    w0.x = f2h(r0.x); w0.y = f2h(r1.x); w0.z = f2h(r2.x); w0.w = f2h(r3.x);
    w1.x = f2h(r0.y); w1.y = f2h(r1.y); w1.z = f2h(r2.y); w1.w = f2h(r3.y);
    w2.x = f2h(r0.z); w2.y = f2h(r1.z); w2.z = f2h(r2.z); w2.w = f2h(r3.z);
    w3.x = f2h(r0.w); w3.y = f2h(r1.w); w3.z = f2h(r2.w); w3.w = f2h(r3.w);
    *(ushort4*)&xs[n4 + 0][c0] = w0;
    *(ushort4*)&xs[n4 + 1][c0] = w1;
    *(ushort4*)&xs[n4 + 2][c0] = w2;
    *(ushort4*)&xs[n4 + 3][c0] = w3;
  }
  __syncthreads();                     // xs ready

  const int wv = t >> 6, lane = t & 63;
  const int quad = lane >> 4, l16 = lane & 15;

  for (int which = 0; which < 3; ++which) {
    const float* W = (which == 0) ? Wq : (which == 1) ? Wk : Wv;
#pragma unroll
    for (int i = 0; i < 16; ++i) {     // stage W: fp32 -> fp16
      int slot = t + 256 * i;
      int o = slot >> 5, c4 = (slot & 31) * 4;
      float4 w4 = *(const float4*)&W[o * CC + c4];
      ushort4 p; p.x = f2h(w4.x); p.y = f2h(w4.y); p.z = f2h(w4.z); p.w = f2h(w4.w);
      *(ushort4*)&Wh[o][c4] = p;
    }
    __syncthreads();                   // Wh ready

    if (which < 2) {                   // q,k: D[o][n]
      ushort* out = (which == 0) ? qT : kT;
      f4 acc[2][2];
#pragma unroll
      for (int ot = 0; ot < 2; ++ot)
#pragma unroll
        for (int nt = 0; nt < 2; ++nt) acc[ot][nt] = (f4){0.f, 0.f, 0.f, 0.f};
#pragma unroll
      for (int kk = 0; kk < 4; ++kk) {
        h8 a0 = *(const h8*)&Wh[(wv * 2 + 0) * 16 + l16][kk * 32 + quad * 8];
        h8 a1 = *(const h8*)&Wh[(wv * 2 + 1) * 16 + l16][kk * 32 + quad * 8];
#pragma unroll
        for (int nt = 0; nt < 2; ++nt) {
          h8 bb = *(const h8*)&xs[nt * 16 + l16][kk * 32 + quad * 8];
          acc[0][nt] = MFMA16(a0, bb, acc[0][nt]);
          acc[1][nt] = MFMA16(a1, bb, acc[1][nt]);
        }
      }
#pragma unroll
      for (int ot = 0; ot < 2; ++ot)
#pragma unroll
        for (int nt = 0; nt < 2; ++nt) {
          f4 a = acc[ot][nt];
          ushort4 p; p.x = f2h(a[0]); p.y = f2h(a[1]); p.z = f2h(a[2]); p.w = f2h(a[3]);
          *(ushort4*)&out[((size_t)b * NN + n0 + nt * 16 + l16) * CC +
                          (wv * 2 + ot) * 16 + quad * 4] = p;
        }
    } else {                           // v: D[n][c]
      f4 acc[2][2];
#pragma unroll
      for (int ci = 0; ci < 2; ++ci)
#pragma unroll
        for (int nt = 0; nt < 2; ++nt) acc[ci][nt] = (f4){0.f, 0.f, 0.f, 0.f};
#pragma unroll
      for (int kk = 0; kk < 4; ++kk) {
        h8 a0 = *(const h8*)&xs[0 * 16 + l16][kk * 32 + quad * 8];
        h8 a1 = *(const h8*)&xs[1 * 16 + l16][kk * 32 + quad * 8];
        h8 b0 = *(const h8*)&Wh[(wv * 2 + 0) * 16 + l16][kk * 32 + quad * 8];
        h8 b1 = *(const h8*)&Wh[(wv * 2 + 1) * 16 + l16][kk * 32 + quad * 8];
        acc[0][0] = MFMA16(a0, b0, acc[0][0]);
        acc[0][1] = MFMA16(a1, b0, acc[0][1]);
        acc[1][0] = MFMA16(a0, b1, acc[1][0]);
        acc[1][1] = MFMA16(a1, b1, acc[1][1]);
      }
#pragma unroll
      for (int ci = 0; ci < 2; ++ci)
#pragma unroll
        for (int nt = 0; nt < 2; ++nt) {
          f4 a = acc[ci][nt];
          ushort4 p; p.x = f2bf(a[0]); p.y = f2bf(a[1]); p.z = f2bf(a[2]); p.w = f2bf(a[3]);
          *(ushort4*)&vB[((size_t)b * CC + (wv * 2 + ci) * 16 + l16) * NN +
                         n0 + nt * 16 + quad * 4] = p;
        }
    }
    __syncthreads();                   // all reads of Wh done before restage
  }
}

// ---------------- kernel B: 4-way split-K flash, TK=64 (R7 shape x R10 occupancy) ----
// Proven loop topology only: stage -> barrier -> prefetch -> compute -> barrier.
// LDS 44 KB -> 2 blocks/CU at grid 512. 32 barriers/block (was 64 at TK=32).
__global__ __launch_bounds__(256) void attn_split(
    const ushort* __restrict__ qTg, const ushort* __restrict__ kTg,
    const ushort* __restrict__ vBg, ushort* __restrict__ Op,
    float* __restrict__ Lg) {
  __shared__ ushort ksT[TK][136];      // [m][c] fp16, 17 KB
  __shared__ ushort vs[CC][72];        // [c][m] bf16, 18 KB
  __shared__ ushort psb[4][16][72];    // per-wave P [q][m] bf16, 9 KB

  const int t = threadIdx.x;
  const int b = blockIdx.z;
  const int split = blockIdx.y;
  const int n0 = blockIdx.x * 64;
  const int wv = t >> 6;
  const int lane = t & 63;
  const int quad = lane >> 4;
  const int l16 = lane & 15;
  const int nw = n0 + wv * 16;
  const int m00 = split * (NN / NSPLIT);

  // staging geometry (R7-proven): K 64x128 fp16, V 128x64 bf16, 4 int4 each
  const int krow = t >> 4, kcol = (t & 15) * 8;
  const int vrow = t >> 3, vcol = (t & 7) * 8;
  const ushort* kbp = kTg + ((size_t)b * NN + m00 + krow) * CC + kcol;
  const ushort* vbp = vBg + ((size_t)b * CC + vrow) * NN + m00 + vcol;

  // Q frags direct from global (Q layout [b][n][c] == A-frag layout)
  const size_t qb = ((size_t)b * NN + nw + l16) * CC + quad * 8;
  h8 aq0 = *(const h8*)&qTg[qb + 0 * 32];
  h8 aq1 = *(const h8*)&qTg[qb + 1 * 32];
  h8 aq2 = *(const h8*)&qTg[qb + 2 * 32];
  h8 aq3 = *(const h8*)&qTg[qb + 3 * 32];

  // prefetch tile 0 (NAMED scalars — R4 lesson)
  int4 k0 = *(const int4*)&kbp[0];
  int4 k1 = *(const int4*)&kbp[16 * CC];
  int4 k2 = *(const int4*)&kbp[32 * CC];
  int4 k3 = *(const int4*)&kbp[48 * CC];
  int4 v0 = *(const int4*)&vbp[0];
  int4 v1 = *(const int4*)&vbp[(size_t)32 * NN];
  int4 v2 = *(const int4*)&vbp[(size_t)64 * NN];
  int4 v3 = *(const int4*)&vbp[(size_t)96 * NN];

  s8 ones;
#pragma unroll
  for (int i = 0; i < 8; ++i) ones[i] = (short)0x3F80;  // bf16 1.0

  f4 o0 = {0,0,0,0}, o1 = {0,0,0,0}, o2 = {0,0,0,0}, o3 = {0,0,0,0};
  f4 o4 = {0,0,0,0}, o5 = {0,0,0,0}, o6 = {0,0,0,0}, o7 = {0,0,0,0};
  f4 oL = {0,0,0,0};

  for (int kt = 0; kt < ITERS; ++kt) {
    *(int4*)&ksT[krow][kcol]      = k0;
    *(int4*)&ksT[krow + 16][kcol] = k1;
    *(int4*)&ksT[krow + 32][kcol] = k2;
    *(int4*)&ksT[krow + 48][kcol] = k3;
    *(int4*)&vs[vrow][vcol]       = v0;
    *(int4*)&vs[vrow + 32][vcol]  = v1;
    *(int4*)&vs[vrow + 64][vcol]  = v2;
    *(int4*)&vs[vrow + 96][vcol]  = v3;
    __syncthreads();                   // K,V ready

    {  // prefetch next tile (drains over compute)
      int ktn = (kt + 1 < ITERS) ? kt + 1 : kt;
      const ushort* kp = kbp + (size_t)ktn * TK * CC;
      const ushort* vp = vbp + (size_t)ktn * TK;
      k0 = *(const int4*)&kp[0];
      k1 = *(const int4*)&kp[16 * CC];
      k2 = *(const int4*)&kp[32 * CC];
      k3 = *(const int4*)&kp[48 * CC];
      v0 = *(const int4*)&vp[0];
      v1 = *(const int4*)&vp[(size_t)32 * NN];
      v2 = *(const int4*)&vp[(size_t)64 * NN];
      v3 = *(const int4*)&vp[(size_t)96 * NN];
    }

    // scores: S[16q][64m], all in-wave (16 MFMA)
    f4 s0 = {0,0,0,0}, s1 = {0,0,0,0}, s2 = {0,0,0,0}, s3 = {0,0,0,0};
#pragma unroll
    for (int kk = 0; kk < 4; ++kk) {
      h8 a = (kk == 0) ? aq0 : (kk == 1) ? aq1 : (kk == 2) ? aq2 : aq3;
      h8 b0 = *(const h8*)&ksT[l16][kk * 32 + quad * 8];
      h8 b1 = *(const h8*)&ksT[16 + l16][kk * 32 + quad * 8];
      h8 b2 = *(const h8*)&ksT[32 + l16][kk * 32 + quad * 8];
      h8 b3 = *(const h8*)&ksT[48 + l16][kk * 32 + quad * 8];
      s0 = MFMA16(a, b0, s0);
      s1 = MFMA16(a, b1, s1);
      s2 = MFMA16(a, b2, s2);
      s3 = MFMA16(a, b3, s3);
    }

    // max-free softmax: straight-line exp + bf16 pack (same-wave LDS, in-order)
#pragma unroll
    for (int r = 0; r < 4; ++r) {
      int row = quad * 4 + r;
      psb[wv][row][l16]      = f2bf(__expf(s0[r]));
      psb[wv][row][16 + l16] = f2bf(__expf(s1[r]));
      psb[wv][row][32 + l16] = f2bf(__expf(s2[r]));
      psb[wv][row][48 + l16] = f2bf(__expf(s3[r]));
    }

    // PV (bf16): D[c=128][q=16], K=64 in 2 steps + L via ones-MFMA
#pragma unroll
    for (int mk = 0; mk < 2; ++mk) {
      s8 bp = *(const s8*)&psb[wv][l16][mk * 32 + quad * 8];
      s8 a0 = *(const s8*)&vs[0 * 16 + l16][mk * 32 + quad * 8];
      s8 a1 = *(const s8*)&vs[1 * 16 + l16][mk * 32 + quad * 8];
      s8 a2 = *(const s8*)&vs[2 * 16 + l16][mk * 32 + quad * 8];
      s8 a3 = *(const s8*)&vs[3 * 16 + l16][mk * 32 + quad * 8];
      o0 = MFMAB(a0, bp, o0);
      o1 = MFMAB(a1, bp, o1);
      o2 = MFMAB(a2, bp, o2);
      o3 = MFMAB(a3, bp, o3);
      s8 a4 = *(const s8*)&vs[4 * 16 + l16][mk * 32 + quad * 8];
      s8 a5 = *(const s8*)&vs[5 * 16 + l16][mk * 32 + quad * 8];
      s8 a6 = *(const s8*)&vs[6 * 16 + l16][mk * 32 + quad * 8];
      s8 a7 = *(const s8*)&vs[7 * 16 + l16][mk * 32 + quad * 8];
      o4 = MFMAB(a4, bp, o4);
      o5 = MFMAB(a5, bp, o5);
      o6 = MFMAB(a6, bp, o6);
      o7 = MFMAB(a7, bp, o7);
      oL = MFMAB(ones, bp, oL);
    }
    __syncthreads();                   // all waves done reading ksT/vs
  }

  // epilogue: bf16 O partial [split*NB+b][n][c], packed 8B stores
  if (quad == 0)
    Lg[((size_t)(split * NB + b)) * NN + nw + l16] = oL[0];
  {
    size_t nb_ = ((size_t)(split * NB + b) * NN + nw + l16) * CC + quad * 4;
    ushort4 p;
#define STORE_O(oo, off) \
    p.x = f2bf(oo[0]); p.y = f2bf(oo[1]); p.z = f2bf(oo[2]); p.w = f2bf(oo[3]); \
    *(ushort4*)&Op[nb_ + off] = p;
    STORE_O(o0, 0 * 16) STORE_O(o1, 1 * 16) STORE_O(o2, 2 * 16) STORE_O(o3, 3 * 16)
    STORE_O(o4, 4 * 16) STORE_O(o5, 5 * 16) STORE_O(o6, 6 * 16) STORE_O(o7, 7 * 16)
#undef STORE_O
  }
}

// ---------------- kernel C: combine 4 splits + Wo projection + residual + GN stats ----
// Unchanged from R12 (passing).
__global__ __launch_bounds__(256) void proj_mm(
    const float* __restrict__ x, const float* __restrict__ Wo,
    const ushort* __restrict__ Op, const float* __restrict__ Lg,
    float* __restrict__ y, float* __restrict__ stats) {
  __shared__ ushort Wh[CC][136];
  __shared__ ushort hT[32][136];
  __shared__ float Linv[32];
  const int t = threadIdx.x;
  const int n0 = blockIdx.x * 32;
  const int b = blockIdx.y;

#pragma unroll
  for (int i = 0; i < 16; ++i) {       // stage Wo -> fp16
    int slot = t + 256 * i;
    int o = slot >> 5, c4 = (slot & 31) * 4;
    float4 w4 = *(const float4*)&Wo[o * CC + c4];
    ushort4 p; p.x = f2h(w4.x); p.y = f2h(w4.y); p.z = f2h(w4.z); p.w = f2h(w4.w);
    *(ushort4*)&Wh[o][c4] = p;
  }
  if (t < 32) {
    float l = 0.f;
#pragma unroll
    for (int s = 0; s < NSPLIT; ++s)
      l += Lg[(size_t)(s * NB + b) * NN + n0 + t];
    Linv[t] = 1.f / l;
  }
  __syncthreads();

#pragma unroll
  for (int i = 0; i < 16; ++i) {       // combine 4 bf16 splits -> h^T fp16
    int slot = t + 256 * i;
    int n = slot >> 5, c4 = (slot & 31) * 4;
    size_t base = ((size_t)(n0 + n)) * CC + c4;
    float a0 = 0.f, a1 = 0.f, a2 = 0.f, a3 = 0.f;
#pragma unroll
    for (int s = 0; s < NSPLIT; ++s) {
      ushort4 u = *(const ushort4*)&Op[(size_t)(s * NB + b) * NN * CC + base];
      a0 += bf2f(u.x); a1 += bf2f(u.y); a2 += bf2f(u.z); a3 += bf2f(u.w);
    }
    float li = Linv[n];
    ushort4 p;
    p.x = f2h(a0 * li); p.y = f2h(a1 * li);
    p.z = f2h(a2 * li); p.w = f2h(a3 * li);
    *(ushort4*)&hT[n][c4] = p;
  }
  __syncthreads();

  const int wv = t >> 6, lane = t & 63;
  const int quad = lane >> 4, l16 = lane & 15;

  f4 acc[2][2];                        // [nt][ot]
#pragma unroll
  for (int nt = 0; nt < 2; ++nt)
#pragma unroll
    for (int ot = 0; ot < 2; ++ot) acc[nt][ot] = (f4){0.f, 0.f, 0.f, 0.f};
#pragma unroll
  for (int kk = 0; kk < 4; ++kk) {
    h8 a0 = *(const h8*)&hT[0 * 16 + l16][kk * 32 + quad * 8];
    h8 a1 = *(const h8*)&hT[1 * 16 + l16][kk * 32 + quad * 8];
    h8 b0 = *(const h8*)&Wh[(wv * 2 + 0) * 16 + l16][kk * 32 + quad * 8];
    h8 b1 = *(const h8*)&Wh[(wv * 2 + 1) * 16 + l16][kk * 32 + quad * 8];
    acc[0][0] = MFMA16(a0, b0, acc[0][0]);
    acc[0][1] = MFMA16(a0, b1, acc[0][1]);
    acc[1][0] = MFMA16(a1, b0, acc[1][0]);
    acc[1][1] = MFMA16(a1, b1, acc[1][1]);
  }

#pragma unroll
  for (int ot = 0; ot < 2; ++ot) {     // store y + residual, gather GN stats
    const int o = (wv * 2 + ot) * 16 + l16;
    const int g = wv * 2 + ot;         // group index (16 ch/group)
    float s = 0.f, sq = 0.f;
#pragma unroll
    for (int nt = 0; nt < 2; ++nt) {
      size_t addr = ((size_t)b * CC + o) * NN + n0 + nt * 16 + quad * 4;
      float4 xv = *(const float4*)&x[addr];
      f4 a = acc[nt][ot];
      float4 yy;
      yy.x = a[0] + xv.x; yy.y = a[1] + xv.y;
      yy.z = a[2] + xv.z; yy.w = a[3] + xv.w;
      *(float4*)&y[addr] = yy;
      s += yy.x + yy.y + yy.z + yy.w;
      sq += yy.x * yy.x + yy.y * yy.y + yy.z * yy.z + yy.w * yy.w;
    }
#pragma unroll
    for (int off = 1; off < 64; off <<= 1) {
      s += __shfl_xor(s, off);
      sq += __shfl_xor(sq, off);
    }
    if (lane == 0) {
      atomicAdd(&stats[(b * 8 + g) * 2 + 0], s);
      atomicAdd(&stats[(b * 8 + g) * 2 + 1], sq);
    }
  }
}

// ---------------- kernel D: GroupNorm finalize + affine + SiLU ----------------
__global__ __launch_bounds__(256) void gn_silu(
    const float* __restrict__ y, const float* __restrict__ stats,
    const float* __restrict__ gamma, const float* __restrict__ beta,
    float* __restrict__ out) {
  const int tid = blockIdx.x * 256 + threadIdx.x;
  const int i4 = tid * 4;
  const int c = (i4 >> 12) & (CC - 1);
  const int b = i4 >> 19;
  const int g = c >> 4;
  const float inv = 1.f / 65536.f;
  float sum = stats[(b * 8 + g) * 2 + 0];
  float sq  = stats[(b * 8 + g) * 2 + 1];
  float mean = sum * inv;
  float var = sq * inv - mean * mean;
  float rs = rsqrtf(var + 1e-5f);
  float ga = gamma[c], be = beta[c];
  float4 v4 = *(const float4*)&y[i4];
  float4 r;
  float o;
  o = (v4.x - mean) * rs * ga + be; r.x = o / (1.f + __expf(-o));
  o = (v4.y - mean) * rs * ga + be; r.y = o / (1.f + __expf(-o));
  o = (v4.z - mean) * rs * ga + be; r.z = o / (1.f + __expf(-o));
  o = (v4.w - mean) * rs * ga + be; r.w = o / (1.f + __expf(-o));
  *(float4*)&out[i4] = r;
}

extern "C" void kernel_launch(void* const* d_in, const int* in_sizes, int n_in,
                              void* d_out, int out_size, void* d_ws, size_t ws_size,
                              hipStream_t stream) {
  const float* x     = (const float*)d_in[0];
  const float* Wq    = (const float*)d_in[1];
  const float* Wk    = (const float*)d_in[2];
  const float* Wv    = (const float*)d_in[3];
  const float* Wo    = (const float*)d_in[4];
  const float* gamma = (const float*)d_in[5];
  const float* beta  = (const float*)d_in[6];
  float* out = (float*)d_out;
  float* ws  = (float*)d_ws;

  // ws layout (MiB), total ~14.1 — keep under 16 (R1 lesson):
  // [0,8):    O partials bf16 [4 splits][b][n][c]
  // [8,10):   qT fp16; [10,12): kT fp16;  y fp32 overlays [8,12) (qT/kT dead)
  // [12,14):  vB bf16
  // [14,...): Lg (128 KB) + stats (128 B)
  const size_t M = (size_t)NB * CC * NN;  // 1,048,576 elems
  ushort* Op = (ushort*)ws;               // 4*M ushorts = 8 MB
  ushort* qT = (ushort*)(ws + 2 * M);
  ushort* kT = qT + M;
  float* y = ws + 2 * M;
  ushort* vB = kT + M;
  float* Lg = (float*)(vB + M);
  float* stats = Lg + (size_t)NSPLIT * NB * NN;

  qkv_mm<<<dim3(NN / 32, NB), 256, 0, stream>>>(x, Wq, Wk, Wv, qT, kT, vB, stats);
  attn_split<<<dim3(NN / 64, NSPLIT, NB), 256, 0, stream>>>(qT, kT, vB, Op, Lg);
  proj_mm<<<dim3(NN / 32, NB), 256, 0, stream>>>(x, Wo, Op, Lg, y, stats);
  gn_silu<<<dim3((int)(M / 1024)), 256, 0, stream>>>(y, stats, gamma, beta, out);
}

// Round 14
// 146.598 us; speedup vs baseline: 1.0282x; 1.0108x over previous
//
#include <hip/hip_runtime.h>

#define CC 128
#define NN 4096
#define NB 2
#define NSPLIT 4
#define TK 64
#define ITERS 16   // 1024 keys per split / TK

typedef unsigned short ushort;
typedef unsigned int uint;
typedef __attribute__((ext_vector_type(8))) _Float16 h8;  // 8 f16 (4 VGPRs)
typedef __attribute__((ext_vector_type(8))) short s8;     // 8 bf16 (4 VGPRs)
typedef __attribute__((ext_vector_type(4))) float f4;     // 4 fp32 acc
#define MFMA16(a, b, c) __builtin_amdgcn_mfma_f32_16x16x32_f16(a, b, c, 0, 0, 0)
#define MFMAB(a, b, c)  __builtin_amdgcn_mfma_f32_16x16x32_bf16(a, b, c, 0, 0, 0)

__device__ __forceinline__ ushort f2h(float f) {
  _Float16 h = (_Float16)f;
  return *(ushort*)&h;
}
__device__ __forceinline__ ushort f2bf(float f) {
  uint u = __float_as_uint(f);
  u += 0x7fffu + ((u >> 16) & 1u);   // round-to-nearest-even
  return (ushort)(u >> 16);
}
__device__ __forceinline__ float bf2f(ushort u) {
  return __uint_as_float((uint)u << 16);
}

// ---------------- kernel A: MERGED q/k/v projections (x read ONCE) ----------------
// Unchanged from R13 (passing).
__global__ __launch_bounds__(256) void qkv_mm(
    const float* __restrict__ x, const float* __restrict__ Wq,
    const float* __restrict__ Wk, const float* __restrict__ Wv,
    ushort* __restrict__ qT, ushort* __restrict__ kT, ushort* __restrict__ vB,
    float* __restrict__ stats) {
  __shared__ ushort Wh[CC][136];     // fp16 W, +8 pad (2-way banks = free)
  __shared__ ushort xs[32][136];     // fp16 x^T tile [n][c]
  const int t = threadIdx.x;
  const int n0 = blockIdx.x * 32;
  const int b = blockIdx.y;

  if (blockIdx.x == 0 && b == 0 && t < 32) stats[t] = 0.f;

  {  // stage x tile with 4x4 register transpose: one slot per thread
    int c0 = (t & 31) * 4;
    int n4 = (t >> 5) * 4;
    float4 r0 = *(const float4*)&x[((size_t)b * CC + c0 + 0) * NN + n0 + n4];
    float4 r1 = *(const float4*)&x[((size_t)b * CC + c0 + 1) * NN + n0 + n4];
    float4 r2 = *(const float4*)&x[((size_t)b * CC + c0 + 2) * NN + n0 + n4];
    float4 r3 = *(const float4*)&x[((size_t)b * CC + c0 + 3) * NN + n0 + n4];
    ushort4 w0, w1, w2, w3;
    w0.x = f2h(r0.x); w0.y = f2h(r1.x); w0.z = f2h(r2.x); w0.w = f2h(r3.x);
    w1.x = f2h(r0.y); w1.y = f2h(r1.y); w1.z = f2h(r2.y); w1.w = f2h(r3.y);
    w2.x = f2h(r0.z); w2.y = f2h(r1.z); w2.z = f2h(r2.z); w2.w = f2h(r3.z);
    w3.x = f2h(r0.w); w3.y = f2h(r1.w); w3.z = f2h(r2.w); w3.w = f2h(r3.w);
    *(ushort4*)&xs[n4 + 0][c0] = w0;
    *(ushort4*)&xs[n4 + 1][c0] = w1;
    *(ushort4*)&xs[n4 + 2][c0] = w2;
    *(ushort4*)&xs[n4 + 3][c0] = w3;
  }
  __syncthreads();                     // xs ready

  const int wv = t >> 6, lane = t & 63;
  const int quad = lane >> 4, l16 = lane & 15;

  for (int which = 0; which < 3; ++which) {
    const float* W = (which == 0) ? Wq : (which == 1) ? Wk : Wv;
#pragma unroll
    for (int i = 0; i < 16; ++i) {     // stage W: fp32 -> fp16
      int slot = t + 256 * i;
      int o = slot >> 5, c4 = (slot & 31) * 4;
      float4 w4 = *(const float4*)&W[o * CC + c4];
      ushort4 p; p.x = f2h(w4.x); p.y = f2h(w4.y); p.z = f2h(w4.z); p.w = f2h(w4.w);
      *(ushort4*)&Wh[o][c4] = p;
    }
    __syncthreads();                   // Wh ready

    if (which < 2) {                   // q,k: D[o][n]
      ushort* out = (which == 0) ? qT : kT;
      f4 acc[2][2];
#pragma unroll
      for (int ot = 0; ot < 2; ++ot)
#pragma unroll
        for (int nt = 0; nt < 2; ++nt) acc[ot][nt] = (f4){0.f, 0.f, 0.f, 0.f};
#pragma unroll
      for (int kk = 0; kk < 4; ++kk) {
        h8 a0 = *(const h8*)&Wh[(wv * 2 + 0) * 16 + l16][kk * 32 + quad * 8];
        h8 a1 = *(const h8*)&Wh[(wv * 2 + 1) * 16 + l16][kk * 32 + quad * 8];
#pragma unroll
        for (int nt = 0; nt < 2; ++nt) {
          h8 bb = *(const h8*)&xs[nt * 16 + l16][kk * 32 + quad * 8];
          acc[0][nt] = MFMA16(a0, bb, acc[0][nt]);
          acc[1][nt] = MFMA16(a1, bb, acc[1][nt]);
        }
      }
#pragma unroll
      for (int ot = 0; ot < 2; ++ot)
#pragma unroll
        for (int nt = 0; nt < 2; ++nt) {
          f4 a = acc[ot][nt];
          ushort4 p; p.x = f2h(a[0]); p.y = f2h(a[1]); p.z = f2h(a[2]); p.w = f2h(a[3]);
          *(ushort4*)&out[((size_t)b * NN + n0 + nt * 16 + l16) * CC +
                          (wv * 2 + ot) * 16 + quad * 4] = p;
        }
    } else {                           // v: D[n][c]
      f4 acc[2][2];
#pragma unroll
      for (int ci = 0; ci < 2; ++ci)
#pragma unroll
        for (int nt = 0; nt < 2; ++nt) acc[ci][nt] = (f4){0.f, 0.f, 0.f, 0.f};
#pragma unroll
      for (int kk = 0; kk < 4; ++kk) {
        h8 a0 = *(const h8*)&xs[0 * 16 + l16][kk * 32 + quad * 8];
        h8 a1 = *(const h8*)&xs[1 * 16 + l16][kk * 32 + quad * 8];
        h8 b0 = *(const h8*)&Wh[(wv * 2 + 0) * 16 + l16][kk * 32 + quad * 8];
        h8 b1 = *(const h8*)&Wh[(wv * 2 + 1) * 16 + l16][kk * 32 + quad * 8];
        acc[0][0] = MFMA16(a0, b0, acc[0][0]);
        acc[0][1] = MFMA16(a1, b0, acc[0][1]);
        acc[1][0] = MFMA16(a0, b1, acc[1][0]);
        acc[1][1] = MFMA16(a1, b1, acc[1][1]);
      }
#pragma unroll
      for (int ci = 0; ci < 2; ++ci)
#pragma unroll
        for (int nt = 0; nt < 2; ++nt) {
          f4 a = acc[ci][nt];
          ushort4 p; p.x = f2bf(a[0]); p.y = f2bf(a[1]); p.z = f2bf(a[2]); p.w = f2bf(a[3]);
          *(ushort4*)&vB[((size_t)b * CC + (wv * 2 + ci) * 16 + l16) * NN +
                         n0 + nt * 16 + quad * 4] = p;
        }
    }
    __syncthreads();                   // all reads of Wh done before restage
  }
}

// ---------------- kernel B: 4-way split-K flash, S-TRANSPOSED scores ----------------
// Same proven topology as R13 (stage -> barrier -> prefetch -> compute -> barrier).
// Score MFMA operands swapped (A=K-frag, B=Q-frag) so D = S^T: each lane holds
// 4 CONSECUTIVE m at fixed q -> psb written as 4 packed b64 stores (was 16 b16).
// psb layout + PV reads byte-identical to R13.
__global__ __launch_bounds__(256) void attn_split(
    const ushort* __restrict__ qTg, const ushort* __restrict__ kTg,
    const ushort* __restrict__ vBg, ushort* __restrict__ Op,
    float* __restrict__ Lg) {
  __shared__ ushort ksT[TK][136];      // [m][c] fp16, 17 KB
  __shared__ ushort vs[CC][72];        // [c][m] bf16, 18 KB
  __shared__ ushort psb[4][16][72];    // per-wave P [q][m] bf16, 9 KB

  const int t = threadIdx.x;
  const int b = blockIdx.z;
  const int split = blockIdx.y;
  const int n0 = blockIdx.x * 64;
  const int wv = t >> 6;
  const int lane = t & 63;
  const int quad = lane >> 4;
  const int l16 = lane & 15;
  const int nw = n0 + wv * 16;
  const int m00 = split * (NN / NSPLIT);

  // staging geometry: K 64x128 fp16, V 128x64 bf16, 4 int4 each
  const int krow = t >> 4, kcol = (t & 15) * 8;
  const int vrow = t >> 3, vcol = (t & 7) * 8;
  const ushort* kbp = kTg + ((size_t)b * NN + m00 + krow) * CC + kcol;
  const ushort* vbp = vBg + ((size_t)b * CC + vrow) * NN + m00 + vcol;

  // Q frags direct from global (Q layout [b][n][c] == frag layout; used as B-operand)
  const size_t qb = ((size_t)b * NN + nw + l16) * CC + quad * 8;
  h8 aq0 = *(const h8*)&qTg[qb + 0 * 32];
  h8 aq1 = *(const h8*)&qTg[qb + 1 * 32];
  h8 aq2 = *(const h8*)&qTg[qb + 2 * 32];
  h8 aq3 = *(const h8*)&qTg[qb + 3 * 32];

  // prefetch tile 0 (NAMED scalars — R4 lesson)
  int4 k0 = *(const int4*)&kbp[0];
  int4 k1 = *(const int4*)&kbp[16 * CC];
  int4 k2 = *(const int4*)&kbp[32 * CC];
  int4 k3 = *(const int4*)&kbp[48 * CC];
  int4 v0 = *(const int4*)&vbp[0];
  int4 v1 = *(const int4*)&vbp[(size_t)32 * NN];
  int4 v2 = *(const int4*)&vbp[(size_t)64 * NN];
  int4 v3 = *(const int4*)&vbp[(size_t)96 * NN];

  s8 ones;
#pragma unroll
  for (int i = 0; i < 8; ++i) ones[i] = (short)0x3F80;  // bf16 1.0

  f4 o0 = {0,0,0,0}, o1 = {0,0,0,0}, o2 = {0,0,0,0}, o3 = {0,0,0,0};
  f4 o4 = {0,0,0,0}, o5 = {0,0,0,0}, o6 = {0,0,0,0}, o7 = {0,0,0,0};
  f4 oL = {0,0,0,0};

  for (int kt = 0; kt < ITERS; ++kt) {
    *(int4*)&ksT[krow][kcol]      = k0;
    *(int4*)&ksT[krow + 16][kcol] = k1;
    *(int4*)&ksT[krow + 32][kcol] = k2;
    *(int4*)&ksT[krow + 48][kcol] = k3;
    *(int4*)&vs[vrow][vcol]       = v0;
    *(int4*)&vs[vrow + 32][vcol]  = v1;
    *(int4*)&vs[vrow + 64][vcol]  = v2;
    *(int4*)&vs[vrow + 96][vcol]  = v3;
    __syncthreads();                   // K,V ready

    {  // prefetch next tile (drains over compute)
      int ktn = (kt + 1 < ITERS) ? kt + 1 : kt;
      const ushort* kp = kbp + (size_t)ktn * TK * CC;
      const ushort* vp = vbp + (size_t)ktn * TK;
      k0 = *(const int4*)&kp[0];
      k1 = *(const int4*)&kp[16 * CC];
      k2 = *(const int4*)&kp[32 * CC];
      k3 = *(const int4*)&kp[48 * CC];
      v0 = *(const int4*)&vp[0];
      v1 = *(const int4*)&vp[(size_t)32 * NN];
      v2 = *(const int4*)&vp[(size_t)64 * NN];
      v3 = *(const int4*)&vp[(size_t)96 * NN];
    }

    // scores TRANSPOSED: D = S^T[m][q]; A=K-frag (LDS), B=Q-frag (regs).
    // s_t[r] = S[m = 16t + quad*4 + r][q = l16]
    f4 s0 = {0,0,0,0}, s1 = {0,0,0,0}, s2 = {0,0,0,0}, s3 = {0,0,0,0};
#pragma unroll
    for (int kk = 0; kk < 4; ++kk) {
      h8 a = (kk == 0) ? aq0 : (kk == 1) ? aq1 : (kk == 2) ? aq2 : aq3;
      h8 b0 = *(const h8*)&ksT[l16][kk * 32 + quad * 8];
      h8 b1 = *(const h8*)&ksT[16 + l16][kk * 32 + quad * 8];
      h8 b2 = *(const h8*)&ksT[32 + l16][kk * 32 + quad * 8];
      h8 b3 = *(const h8*)&ksT[48 + l16][kk * 32 + quad * 8];
      s0 = MFMA16(b0, a, s0);          // A=K (rows m), B=Q (cols q)
      s1 = MFMA16(b1, a, s1);
      s2 = MFMA16(b2, a, s2);
      s3 = MFMA16(b3, a, s3);
    }

    // max-free softmax: exp + packed b64 psb stores (4 stores, was 16 b16)
    {
      ushort4 pk;
      pk.x = f2bf(__expf(s0[0])); pk.y = f2bf(__expf(s0[1]));
      pk.z = f2bf(__expf(s0[2])); pk.w = f2bf(__expf(s0[3]));
      *(ushort4*)&psb[wv][l16][0 + quad * 4] = pk;
      pk.x = f2bf(__expf(s1[0])); pk.y = f2bf(__expf(s1[1]));
      pk.z = f2bf(__expf(s1[2])); pk.w = f2bf(__expf(s1[3]));
      *(ushort4*)&psb[wv][l16][16 + quad * 4] = pk;
      pk.x = f2bf(__expf(s2[0])); pk.y = f2bf(__expf(s2[1]));
      pk.z = f2bf(__expf(s2[2])); pk.w = f2bf(__expf(s2[3]));
      *(ushort4*)&psb[wv][l16][32 + quad * 4] = pk;
      pk.x = f2bf(__expf(s3[0])); pk.y = f2bf(__expf(s3[1]));
      pk.z = f2bf(__expf(s3[2])); pk.w = f2bf(__expf(s3[3]));
      *(ushort4*)&psb[wv][l16][48 + quad * 4] = pk;
    }
    // same-wave DS is in-order: psb writes visible to reads below

    // PV (bf16): D[c=128][q=16], K=64 in 2 steps + L via ones-MFMA (unchanged)
#pragma unroll
    for (int mk = 0; mk < 2; ++mk) {
      s8 bp = *(const s8*)&psb[wv][l16][mk * 32 + quad * 8];
      s8 a0 = *(const s8*)&vs[0 * 16 + l16][mk * 32 + quad * 8];
      s8 a1 = *(const s8*)&vs[1 * 16 + l16][mk * 32 + quad * 8];
      s8 a2 = *(const s8*)&vs[2 * 16 + l16][mk * 32 + quad * 8];
      s8 a3 = *(const s8*)&vs[3 * 16 + l16][mk * 32 + quad * 8];
      o0 = MFMAB(a0, bp, o0);
      o1 = MFMAB(a1, bp, o1);
      o2 = MFMAB(a2, bp, o2);
      o3 = MFMAB(a3, bp, o3);
      s8 a4 = *(const s8*)&vs[4 * 16 + l16][mk * 32 + quad * 8];
      s8 a5 = *(const s8*)&vs[5 * 16 + l16][mk * 32 + quad * 8];
      s8 a6 = *(const s8*)&vs[6 * 16 + l16][mk * 32 + quad * 8];
      s8 a7 = *(const s8*)&vs[7 * 16 + l16][mk * 32 + quad * 8];
      o4 = MFMAB(a4, bp, o4);
      o5 = MFMAB(a5, bp, o5);
      o6 = MFMAB(a6, bp, o6);
      o7 = MFMAB(a7, bp, o7);
      oL = MFMAB(ones, bp, oL);
    }
    __syncthreads();                   // all waves done reading ksT/vs
  }

  // epilogue: bf16 O partial [split*NB+b][n][c], packed 8B stores
  if (quad == 0)
    Lg[((size_t)(split * NB + b)) * NN + nw + l16] = oL[0];
  {
    size_t nb_ = ((size_t)(split * NB + b) * NN + nw + l16) * CC + quad * 4;
    ushort4 p;
#define STORE_O(oo, off) \
    p.x = f2bf(oo[0]); p.y = f2bf(oo[1]); p.z = f2bf(oo[2]); p.w = f2bf(oo[3]); \
    *(ushort4*)&Op[nb_ + off] = p;
    STORE_O(o0, 0 * 16) STORE_O(o1, 1 * 16) STORE_O(o2, 2 * 16) STORE_O(o3, 3 * 16)
    STORE_O(o4, 4 * 16) STORE_O(o5, 5 * 16) STORE_O(o6, 6 * 16) STORE_O(o7, 7 * 16)
#undef STORE_O
  }
}

// ---------------- kernel C: combine 4 splits + Wo projection + residual + GN stats ----
// Unchanged from R13 (passing).
__global__ __launch_bounds__(256) void proj_mm(
    const float* __restrict__ x, const float* __restrict__ Wo,
    const ushort* __restrict__ Op, const float* __restrict__ Lg,
    float* __restrict__ y, float* __restrict__ stats) {
  __shared__ ushort Wh[CC][136];
  __shared__ ushort hT[32][136];
  __shared__ float Linv[32];
  const int t = threadIdx.x;
  const int n0 = blockIdx.x * 32;
  const int b = blockIdx.y;

#pragma unroll
  for (int i = 0; i < 16; ++i) {       // stage Wo -> fp16
    int slot = t + 256 * i;
    int o = slot >> 5, c4 = (slot & 31) * 4;
    float4 w4 = *(const float4*)&Wo[o * CC + c4];
    ushort4 p; p.x = f2h(w4.x); p.y = f2h(w4.y); p.z = f2h(w4.z); p.w = f2h(w4.w);
    *(ushort4*)&Wh[o][c4] = p;
  }
  if (t < 32) {
    float l = 0.f;
#pragma unroll
    for (int s = 0; s < NSPLIT; ++s)
      l += Lg[(size_t)(s * NB + b) * NN + n0 + t];
    Linv[t] = 1.f / l;
  }
  __syncthreads();

#pragma unroll
  for (int i = 0; i < 16; ++i) {       // combine 4 bf16 splits -> h^T fp16
    int slot = t + 256 * i;
    int n = slot >> 5, c4 = (slot & 31) * 4;
    size_t base = ((size_t)(n0 + n)) * CC + c4;
    float a0 = 0.f, a1 = 0.f, a2 = 0.f, a3 = 0.f;
#pragma unroll
    for (int s = 0; s < NSPLIT; ++s) {
      ushort4 u = *(const ushort4*)&Op[(size_t)(s * NB + b) * NN * CC + base];
      a0 += bf2f(u.x); a1 += bf2f(u.y); a2 += bf2f(u.z); a3 += bf2f(u.w);
    }
    float li = Linv[n];
    ushort4 p;
    p.x = f2h(a0 * li); p.y = f2h(a1 * li);
    p.z = f2h(a2 * li); p.w = f2h(a3 * li);
    *(ushort4*)&hT[n][c4] = p;
  }
  __syncthreads();

  const int wv = t >> 6, lane = t & 63;
  const int quad = lane >> 4, l16 = lane & 15;

  f4 acc[2][2];                        // [nt][ot]
#pragma unroll
  for (int nt = 0; nt < 2; ++nt)
#pragma unroll
    for (int ot = 0; ot < 2; ++ot) acc[nt][ot] = (f4){0.f, 0.f, 0.f, 0.f};
#pragma unroll
  for (int kk = 0; kk < 4; ++kk) {
    h8 a0 = *(const h8*)&hT[0 * 16 + l16][kk * 32 + quad * 8];
    h8 a1 = *(const h8*)&hT[1 * 16 + l16][kk * 32 + quad * 8];
    h8 b0 = *(const h8*)&Wh[(wv * 2 + 0) * 16 + l16][kk * 32 + quad * 8];
    h8 b1 = *(const h8*)&Wh[(wv * 2 + 1) * 16 + l16][kk * 32 + quad * 8];
    acc[0][0] = MFMA16(a0, b0, acc[0][0]);
    acc[0][1] = MFMA16(a0, b1, acc[0][1]);
    acc[1][0] = MFMA16(a1, b0, acc[1][0]);
    acc[1][1] = MFMA16(a1, b1, acc[1][1]);
  }

#pragma unroll
  for (int ot = 0; ot < 2; ++ot) {     // store y + residual, gather GN stats
    const int o = (wv * 2 + ot) * 16 + l16;
    const int g = wv * 2 + ot;         // group index (16 ch/group)
    float s = 0.f, sq = 0.f;
#pragma unroll
    for (int nt = 0; nt < 2; ++nt) {
      size_t addr = ((size_t)b * CC + o) * NN + n0 + nt * 16 + quad * 4;
      float4 xv = *(const float4*)&x[addr];
      f4 a = acc[nt][ot];
      float4 yy;
      yy.x = a[0] + xv.x; yy.y = a[1] + xv.y;
      yy.z = a[2] + xv.z; yy.w = a[3] + xv.w;
      *(float4*)&y[addr] = yy;
      s += yy.x + yy.y + yy.z + yy.w;
      sq += yy.x * yy.x + yy.y * yy.y + yy.z * yy.z + yy.w * yy.w;
    }
#pragma unroll
    for (int off = 1; off < 64; off <<= 1) {
      s += __shfl_xor(s, off);
      sq += __shfl_xor(sq, off);
    }
    if (lane == 0) {
      atomicAdd(&stats[(b * 8 + g) * 2 + 0], s);
      atomicAdd(&stats[(b * 8 + g) * 2 + 1], sq);
    }
  }
}

// ---------------- kernel D: GroupNorm finalize + affine + SiLU ----------------
__global__ __launch_bounds__(256) void gn_silu(
    const float* __restrict__ y, const float* __restrict__ stats,
    const float* __restrict__ gamma, const float* __restrict__ beta,
    float* __restrict__ out) {
  const int tid = blockIdx.x * 256 + threadIdx.x;
  const int i4 = tid * 4;
  const int c = (i4 >> 12) & (CC - 1);
  const int b = i4 >> 19;
  const int g = c >> 4;
  const float inv = 1.f / 65536.f;
  float sum = stats[(b * 8 + g) * 2 + 0];
  float sq  = stats[(b * 8 + g) * 2 + 1];
  float mean = sum * inv;
  float var = sq * inv - mean * mean;
  float rs = rsqrtf(var + 1e-5f);
  float ga = gamma[c], be = beta[c];
  float4 v4 = *(const float4*)&y[i4];
  float4 r;
  float o;
  o = (v4.x - mean) * rs * ga + be; r.x = o / (1.f + __expf(-o));
  o = (v4.y - mean) * rs * ga + be; r.y = o / (1.f + __expf(-o));
  o = (v4.z - mean) * rs * ga + be; r.z = o / (1.f + __expf(-o));
  o = (v4.w - mean) * rs * ga + be; r.w = o / (1.f + __expf(-o));
  *(float4*)&out[i4] = r;
}

extern "C" void kernel_launch(void* const* d_in, const int* in_sizes, int n_in,
                              void* d_out, int out_size, void* d_ws, size_t ws_size,
                              hipStream_t stream) {
  const float* x     = (const float*)d_in[0];
  const float* Wq    = (const float*)d_in[1];
  const float* Wk    = (const float*)d_in[2];
  const float* Wv    = (const float*)d_in[3];
  const float* Wo    = (const float*)d_in[4];
  const float* gamma = (const float*)d_in[5];
  const float* beta  = (const float*)d_in[6];
  float* out = (float*)d_out;
  float* ws  = (float*)d_ws;

  // ws layout (MiB), total ~14.1 — keep under 16 (R1 lesson):
  // [0,8):    O partials bf16 [4 splits][b][n][c]
  // [8,10):   qT fp16; [10,12): kT fp16;  y fp32 overlays [8,12) (qT/kT dead)
  // [12,14):  vB bf16
  // [14,...): Lg (128 KB) + stats (128 B)
  const size_t M = (size_t)NB * CC * NN;  // 1,048,576 elems
  ushort* Op = (ushort*)ws;               // 4*M ushorts = 8 MB
  ushort* qT = (ushort*)(ws + 2 * M);
  ushort* kT = qT + M;
  float* y = ws + 2 * M;
  ushort* vB = kT + M;
  float* Lg = (float*)(vB + M);
  float* stats = Lg + (size_t)NSPLIT * NB * NN;

  qkv_mm<<<dim3(NN / 32, NB), 256, 0, stream>>>(x, Wq, Wk, Wv, qT, kT, vB, stats);
  attn_split<<<dim3(NN / 64, NSPLIT, NB), 256, 0, stream>>>(qT, kT, vB, Op, Lg);
  proj_mm<<<dim3(NN / 32, NB), 256, 0, stream>>>(x, Wo, Op, Lg, y, stats);
  gn_silu<<<dim3((int)(M / 1024)), 256, 0, stream>>>(y, stats, gamma, beta, out);
}